// Round 1
// baseline (195.445 us; speedup 1.0000x reference)
//
#include <hip/hip_runtime.h>

#define NW_CAP 256   // LDS histogram capacity (>= num_windows = 162)
#define CHUNK  256   // items per sort chunk == block size of k_hist/k_order

// ---------------------------------------------------------------------------
// K1: per-chunk histogram. hist[g*NW + w] = #items in chunk g with window w.
// Fully rewritten every launch (no stale-ws dependence, no global atomics).
// ---------------------------------------------------------------------------
__global__ void k_hist(const int* __restrict__ wid, int N, int NW,
                       int* __restrict__ hist) {
    __shared__ int lh[NW_CAP];
    const int t = threadIdx.x;
    for (int w = t; w < NW; w += blockDim.x) lh[w] = 0;
    __syncthreads();
    const int i = blockIdx.x * CHUNK + t;
    if (i < N) atomicAdd(&lh[wid[i]], 1);
    __syncthreads();
    for (int w = t; w < NW; w += blockDim.x) hist[blockIdx.x * NW + w] = lh[w];
}

// ---------------------------------------------------------------------------
// K2: single block. counts[w] = sum_g hist[g][w]; offsets = exclusive scan;
// then hist[g][w] is overwritten with the global base for (chunk g, window w).
// Also emits counts as f32 into d_out's counts section.
// ---------------------------------------------------------------------------
__global__ void k_scan(int* __restrict__ hist, int G, int NW,
                       int* __restrict__ offsets, float* __restrict__ counts_f) {
    __shared__ int cnt[NW_CAP];
    const int t = threadIdx.x;
    if (t < NW) {
        int s = 0;
        for (int g = 0; g < G; ++g) s += hist[g * NW + t];
        cnt[t] = s;
        counts_f[t] = (float)s;
    }
    __syncthreads();
    if (t == 0) {
        int run = 0;
        for (int w = 0; w < NW; ++w) { offsets[w] = run; run += cnt[w]; }
        offsets[NW] = run;
    }
    __syncthreads();
    if (t < NW) {
        int run = offsets[t];
        for (int g = 0; g < G; ++g) {
            int v = hist[g * NW + t];
            hist[g * NW + t] = run;   // base for chunk g, window t
            run += v;
        }
    }
}

// ---------------------------------------------------------------------------
// K3: stable rank within chunk + scatter of order. For item i in chunk g:
//   p = base[g][wid[i]] + (# j < i in chunk with wid[j]==wid[i])
// order_i (ws, int) feeds the gather; order_f is the harness output (f32).
// ---------------------------------------------------------------------------
__global__ void k_order(const int* __restrict__ wid, int N, int NW,
                        const int* __restrict__ base,
                        int* __restrict__ order_i, float* __restrict__ order_f) {
    __shared__ int lw[CHUNK];
    const int t = threadIdx.x;
    const int i = blockIdx.x * CHUNK + t;
    const int w = (i < N) ? wid[i] : -1;
    lw[t] = w;
    __syncthreads();
    if (i < N) {
        int r = 0;
        for (int j = 0; j < t; ++j) r += (lw[j] == w);
        const int p = base[blockIdx.x * NW + w] + r;
        order_i[p] = i;
        order_f[p] = (float)i;
    }
}

// ---------------------------------------------------------------------------
// K4: padded gather. One block per (w, s) output row slot.
// 256 threads = B(8) batches x 32 float4 lanes (C=128 floats per row).
// Writes every windows element exactly once (payload or zero).
// ---------------------------------------------------------------------------
__global__ void k_gather(const float4* __restrict__ x, int N, int NW, int MWS, int B,
                         const int* __restrict__ order_i,
                         const int* __restrict__ offsets,
                         float4* __restrict__ out) {
    const int C4 = 32;                  // 128 floats / 4
    const int slot = blockIdx.x;        // w * MWS + s
    const int w = slot / MWS;
    const int s = slot - w * MWS;
    const int t = threadIdx.x;
    const int b  = t >> 5;              // 0..7
    const int c4 = t & 31;              // 0..31

    const int off = offsets[w];
    const int cnt = offsets[w + 1] - off;

    float4 v = make_float4(0.f, 0.f, 0.f, 0.f);
    if (s < cnt) {
        const int src = order_i[off + s];
        v = x[((long long)b * N + src) * C4 + c4];
    }
    out[(((long long)b * NW + w) * MWS + s) * C4 + c4] = v;
}

// ---------------------------------------------------------------------------
extern "C" void kernel_launch(void* const* d_in, const int* in_sizes, int n_in,
                              void* d_out, int out_size, void* d_ws, size_t ws_size,
                              hipStream_t stream) {
    const float* x   = (const float*)d_in[0];
    const int*   wid = (const int*)d_in[1];

    const int N  = in_sizes[1];                 // 40962
    const int C  = 128;                         // per reference
    const int NW = 162;                         // per reference (num_windows)
    const int B  = (int)((long long)in_sizes[0] / ((long long)N * C));

    const long long win_elems = (long long)out_size - N - NW;
    const int MWS = (int)(win_elems / ((long long)B * NW * C));

    const int G = (N + CHUNK - 1) / CHUNK;      // #chunks

    // ws layout (ints): hist[G*NW] | offsets[NW+1] | order_i[N]
    int* hist    = (int*)d_ws;
    int* offsets = hist + (size_t)G * NW;
    int* order_i = offsets + (NW + 1);

    float* out_f    = (float*)d_out;
    float* order_f  = out_f + win_elems;
    float* counts_f = order_f + N;

    k_hist <<<G, CHUNK, 0, stream>>>(wid, N, NW, hist);
    k_scan <<<1, 256, 0, stream>>>(hist, G, NW, offsets, counts_f);
    k_order<<<G, CHUNK, 0, stream>>>(wid, N, NW, hist, order_i, order_f);
    k_gather<<<NW * MWS, 256, 0, stream>>>((const float4*)x, N, NW, MWS, B,
                                           order_i, offsets, (float4*)out_f);
}

// Round 2
// 150.477 us; speedup vs baseline: 1.2988x; 1.2988x over previous
//
#include <hip/hip_runtime.h>

#define NW_MAX  192   // LDS capacity for per-window arrays (>= 162)
#define CHUNK   512   // items per sort chunk
#define G_CAP   84    // ceil(40962/512)=81, with slack
#define HIST_CAP (G_CAP * NW_MAX < 13500 ? 13500 : G_CAP * NW_MAX) // ints

// ---------------------------------------------------------------------------
// K1: per-chunk histogram. hist[g*NW + w] = #items in chunk g with window w.
// ---------------------------------------------------------------------------
__global__ void k_hist(const int* __restrict__ wid, int N, int NW,
                       int* __restrict__ hist) {
    __shared__ int lh[NW_MAX];
    const int t = threadIdx.x;
    for (int w = t; w < NW; w += blockDim.x) lh[w] = 0;
    __syncthreads();
    const int i = blockIdx.x * CHUNK + t;
    if (i < N) atomicAdd(&lh[wid[i]], 1);
    __syncthreads();
    for (int w = t; w < NW; w += blockDim.x) hist[blockIdx.x * NW + w] = lh[w];
}

// ---------------------------------------------------------------------------
// K2: single block, 1024 threads. Stages the whole hist (G*NW ints, ~52 KB)
// into LDS with coalesced loads, then:
//   counts[w] = sum_g hist[g][w]   (lanes sweep consecutive w -> conflict-free)
//   offsets   = exclusive scan (serial over 162, in LDS)
//   hist[g][w] <- global base for (chunk g, window w)  (running prefix in LDS)
// All global traffic is two coalesced passes over 52 KB.
// ---------------------------------------------------------------------------
__global__ void k_scan(int* __restrict__ hist, int G, int NW,
                       int* __restrict__ offsets, float* __restrict__ counts_f) {
    __shared__ int lh[13608];          // >= 81*162, 53 KB
    __shared__ int cnt[NW_MAX];
    __shared__ int off[NW_MAX + 1];
    const int t = threadIdx.x;
    const int total = G * NW;

    for (int idx = t; idx < total; idx += blockDim.x) lh[idx] = hist[idx];
    __syncthreads();

    if (t < NW) {
        int s = 0;
        for (int g = 0; g < G; ++g) s += lh[g * NW + t];
        cnt[t] = s;
        counts_f[t] = (float)s;
    }
    __syncthreads();

    if (t == 0) {
        int run = 0;
        for (int w = 0; w < NW; ++w) { off[w] = run; run += cnt[w]; }
        off[NW] = run;
    }
    __syncthreads();

    if (t <= NW) offsets[t] = off[t];
    if (t < NW) {
        int run = off[t];
        for (int g = 0; g < G; ++g) {
            int v = lh[g * NW + t];
            lh[g * NW + t] = run;      // base for chunk g, window t
            run += v;
        }
    }
    __syncthreads();

    for (int idx = t; idx < total; idx += blockDim.x) hist[idx] = lh[idx];
}

// ---------------------------------------------------------------------------
// K3: stable rank within chunk, then write BOTH outputs of the sort:
//   order_f[p] = i                      (harness output, f32)
//   slot_src[w*MWS + (p - offsets[w])] = i   (direct slot->source table)
// Padding slots are never written; gather detects them via s >= cnt.
// ---------------------------------------------------------------------------
__global__ void k_order(const int* __restrict__ wid, int N, int NW, int MWS,
                        const int* __restrict__ base,
                        const int* __restrict__ offsets,
                        int* __restrict__ slot_src, float* __restrict__ order_f) {
    __shared__ int lw[CHUNK];
    const int t = threadIdx.x;
    const int i = blockIdx.x * CHUNK + t;
    const int w = (i < N) ? wid[i] : -1;
    lw[t] = w;
    __syncthreads();
    if (i < N) {
        int r = 0;
        for (int j = 0; j < t; ++j) r += (lw[j] == w);   // broadcast LDS reads
        const int p = base[blockIdx.x * NW + w] + r;     // global sorted pos
        order_f[p] = (float)i;
        slot_src[w * MWS + (p - offsets[w])] = i;
    }
}

// ---------------------------------------------------------------------------
// K4: padded gather, 4 slots per block (same window). 256 threads =
// B(8) batches x 32 float4 lanes. slot_src loads hoisted for ILP; every
// output element written exactly once (payload or zero).
// ---------------------------------------------------------------------------
#define SLOTS 4
__global__ void k_gather(const float4* __restrict__ x, int N, int NW, int MWS,
                         int bpw,
                         const int* __restrict__ slot_src,
                         const int* __restrict__ offsets,
                         float4* __restrict__ out) {
    const int C4 = 32;                         // 128 floats / 4
    const int w = blockIdx.x / bpw;
    const int sbase = (blockIdx.x - w * bpw) * SLOTS;
    const int t = threadIdx.x;
    const int b  = t >> 5;
    const int c4 = t & 31;

    const int off = offsets[w];
    const int cnt = offsets[w + 1] - off;

    int srcs[SLOTS];
    #pragma unroll
    for (int si = 0; si < SLOTS; ++si) {
        const int s = sbase + si;
        srcs[si] = (s < cnt) ? slot_src[w * MWS + s] : -1;
    }

    const long long outRow0 = ((long long)b * NW + w) * MWS;
    #pragma unroll
    for (int si = 0; si < SLOTS; ++si) {
        const int s = sbase + si;
        if (s >= MWS) break;
        float4 v = make_float4(0.f, 0.f, 0.f, 0.f);
        if (srcs[si] >= 0)
            v = x[((long long)b * N + srcs[si]) * C4 + c4];
        out[(outRow0 + s) * C4 + c4] = v;
    }
}

// ---------------------------------------------------------------------------
extern "C" void kernel_launch(void* const* d_in, const int* in_sizes, int n_in,
                              void* d_out, int out_size, void* d_ws, size_t ws_size,
                              hipStream_t stream) {
    const float* x   = (const float*)d_in[0];
    const int*   wid = (const int*)d_in[1];

    const int N  = in_sizes[1];                 // 40962
    const int C  = 128;                         // per reference
    const int NW = 162;                         // per reference
    const int B  = (int)((long long)in_sizes[0] / ((long long)N * C));

    const long long win_elems = (long long)out_size - N - NW;
    const int MWS = (int)(win_elems / ((long long)B * NW * C));

    const int G = (N + CHUNK - 1) / CHUNK;      // 81 chunks

    // ws layout (ints): hist[G*NW] | offsets[NW+1] | slot_src[NW*MWS]
    int* hist     = (int*)d_ws;
    int* offsets  = hist + (size_t)G * NW;
    int* slot_src = offsets + (NW + 1);

    float* out_f    = (float*)d_out;
    float* order_f  = out_f + win_elems;
    float* counts_f = order_f + N;

    const int bpw = (MWS + SLOTS - 1) / SLOTS;

    k_hist  <<<G, CHUNK, 0, stream>>>(wid, N, NW, hist);
    k_scan  <<<1, 1024, 0, stream>>>(hist, G, NW, offsets, counts_f);
    k_order <<<G, CHUNK, 0, stream>>>(wid, N, NW, MWS, hist, offsets,
                                      slot_src, order_f);
    k_gather<<<NW * bpw, 256, 0, stream>>>((const float4*)x, N, NW, MWS, bpw,
                                           slot_src, offsets, (float4*)out_f);
}

// Round 3
// 143.914 us; speedup vs baseline: 1.3581x; 1.0456x over previous
//
#include <hip/hip_runtime.h>

typedef float f32x4 __attribute__((ext_vector_type(4)));

#define NW_MAX 192   // LDS capacity for per-window arrays (>= 162)
#define CHUNK  512   // items per sort chunk
#define ROWS   8     // source rows per scatter block
#define PS     8     // slots per pad block

// ---------------------------------------------------------------------------
// K1: per-chunk histogram. hist[g*NW + w] = #items in chunk g with window w.
// ---------------------------------------------------------------------------
__global__ void k_hist(const int* __restrict__ wid, int N, int NW,
                       int* __restrict__ hist) {
    __shared__ int lh[NW_MAX];
    const int t = threadIdx.x;
    for (int w = t; w < NW; w += blockDim.x) lh[w] = 0;
    __syncthreads();
    const int i = blockIdx.x * CHUNK + t;
    if (i < N) atomicAdd(&lh[wid[i]], 1);
    __syncthreads();
    for (int w = t; w < NW; w += blockDim.x) hist[blockIdx.x * NW + w] = lh[w];
}

// ---------------------------------------------------------------------------
// K2: single block, 1024 threads. Stage hist (G*NW ints, ~53 KB) in LDS;
//   counts[w] = sum_g hist[g][w]        (coalesced, conflict-free)
//   offsets   = exclusive scan          (parallel Hillis-Steele over 256)
//   hist[g][w] <- global base for (g,w) (running prefix per window, in LDS)
// ---------------------------------------------------------------------------
__global__ void k_scan(int* __restrict__ hist, int G, int NW,
                       int* __restrict__ offsets, float* __restrict__ counts_f) {
    __shared__ int lh[13608];           // >= 81*162
    __shared__ int cnt[NW_MAX];
    __shared__ int sc[256];
    const int t = threadIdx.x;
    const int total = G * NW;

    for (int idx = t; idx < total; idx += blockDim.x) lh[idx] = hist[idx];
    __syncthreads();

    if (t < NW) {
        int s = 0;
        for (int g = 0; g < G; ++g) s += lh[g * NW + t];
        cnt[t] = s;
        counts_f[t] = (float)s;
    }
    __syncthreads();

    // inclusive scan over 256 lanes (NW <= 256)
    if (t < 256) sc[t] = (t < NW) ? cnt[t] : 0;
    __syncthreads();
    for (int d = 1; d < 256; d <<= 1) {
        int v = 0;
        if (t < 256 && t >= d) v = sc[t - d];
        __syncthreads();
        if (t < 256) sc[t] += v;
        __syncthreads();
    }
    // exclusive offsets
    if (t <= NW) offsets[t] = (t == 0) ? 0 : sc[t - 1];
    __syncthreads();

    if (t < NW) {
        int run = (t == 0) ? 0 : sc[t - 1];
        for (int g = 0; g < G; ++g) {
            int v = lh[g * NW + t];
            lh[g * NW + t] = run;       // base for chunk g, window t
            run += v;
        }
    }
    __syncthreads();

    for (int idx = t; idx < total; idx += blockDim.x) hist[idx] = lh[idx];
}

// ---------------------------------------------------------------------------
// K3: stable rank within chunk; write order (f32, harness output) and the
// source-major slot table pos_i[i] = p - offsets[w]  (coalesced in i).
// ---------------------------------------------------------------------------
__global__ void k_order(const int* __restrict__ wid, int N, int NW,
                        const int* __restrict__ base,
                        const int* __restrict__ offsets,
                        int* __restrict__ pos_i, float* __restrict__ order_f) {
    __shared__ int lw[CHUNK];
    const int t = threadIdx.x;
    const int i = blockIdx.x * CHUNK + t;
    const int w = (i < N) ? wid[i] : -1;
    lw[t] = w;
    __syncthreads();
    if (i < N) {
        int r = 0;
        for (int j = 0; j < t; ++j) r += (lw[j] == w);   // broadcast LDS reads
        const int p = base[blockIdx.x * NW + w] + r;     // global sorted pos
        order_f[p] = (float)i;
        pos_i[i] = p - offsets[w];                       // slot within window
    }
}

// ---------------------------------------------------------------------------
// K4: scatter. Source rows in order: reads are 8 dense sequential streams
// (one per batch); writes are dense ascending streams per (b, window).
// 256 threads = 8 batches x 32 f32x4 lanes; ROWS rows per block for ILP.
// ---------------------------------------------------------------------------
__global__ void k_scatter(const f32x4* __restrict__ x,
                          const int* __restrict__ wid,
                          const int* __restrict__ pos_i,
                          int N, int NW, int MWS,
                          f32x4* __restrict__ out) {
    const int t = threadIdx.x;
    const int b  = t >> 5;
    const int c4 = t & 31;
    const int i0 = blockIdx.x * ROWS;
    #pragma unroll
    for (int r = 0; r < ROWS; ++r) {
        const int i = i0 + r;                  // uniform across block
        if (i >= N) break;
        const int w = wid[i];                  // scalarized (uniform)
        const int s = pos_i[i];
        f32x4 v = __builtin_nontemporal_load(&x[((long long)b * N + i) * 32 + c4]);
        __builtin_nontemporal_store(v,
            &out[(((long long)b * NW + w) * MWS + s) * 32 + c4]);
    }
}

// ---------------------------------------------------------------------------
// K5: zero-fill padding slots (s >= cnt[w]) only. Blocks whose slot range is
// entirely data exit immediately; pad writes are dense per (b, window).
// ---------------------------------------------------------------------------
__global__ void k_pad(const int* __restrict__ offsets, int NW, int MWS, int bpw,
                      f32x4* __restrict__ out) {
    const int w  = blockIdx.x / bpw;
    const int sb = (blockIdx.x - w * bpw) * PS;
    const int cnt = offsets[w + 1] - offsets[w];
    if (sb + PS <= cnt) return;                // all-data block: nothing to do
    const int t = threadIdx.x;
    const int b  = t >> 5;
    const int c4 = t & 31;
    const f32x4 z = {0.f, 0.f, 0.f, 0.f};
    for (int r = 0; r < PS; ++r) {
        const int s = sb + r;
        if (s >= MWS) break;
        if (s < cnt) continue;
        __builtin_nontemporal_store(z,
            &out[(((long long)b * NW + w) * MWS + s) * 32 + c4]);
    }
}

// ---------------------------------------------------------------------------
extern "C" void kernel_launch(void* const* d_in, const int* in_sizes, int n_in,
                              void* d_out, int out_size, void* d_ws, size_t ws_size,
                              hipStream_t stream) {
    const float* x   = (const float*)d_in[0];
    const int*   wid = (const int*)d_in[1];

    const int N  = in_sizes[1];                 // 40962
    const int C  = 128;                         // per reference
    const int NW = 162;                         // per reference
    const int B  = (int)((long long)in_sizes[0] / ((long long)N * C));

    const long long win_elems = (long long)out_size - N - NW;
    const int MWS = (int)(win_elems / ((long long)B * NW * C));

    const int G = (N + CHUNK - 1) / CHUNK;      // 81 chunks

    // ws layout (ints): hist[G*NW] | offsets[NW+1] | pos_i[N]
    int* hist    = (int*)d_ws;
    int* offsets = hist + (size_t)G * NW;
    int* pos_i   = offsets + (NW + 1);

    float* out_f    = (float*)d_out;
    float* order_f  = out_f + win_elems;
    float* counts_f = order_f + N;

    const int sblocks = (N + ROWS - 1) / ROWS;
    const int bpw     = (MWS + PS - 1) / PS;

    k_hist   <<<G, CHUNK, 0, stream>>>(wid, N, NW, hist);
    k_scan   <<<1, 1024, 0, stream>>>(hist, G, NW, offsets, counts_f);
    k_order  <<<G, CHUNK, 0, stream>>>(wid, N, NW, hist, offsets,
                                       pos_i, order_f);
    k_pad    <<<NW * bpw, 256, 0, stream>>>(offsets, NW, MWS, bpw,
                                            (f32x4*)out_f);
    k_scatter<<<sblocks, 256, 0, stream>>>((const f32x4*)x, wid, pos_i,
                                           N, NW, MWS, (f32x4*)out_f);
}